// Round 22
// baseline (228.351 us; speedup 1.0000x reference)
//
#include <hip/hip_runtime.h>

// B=8, L=2048, D=512, H=512, E=256, K=30.  fp32 I/O, x_lengths int32.
// Identity: softmax -> key-mask -> renorm -> top-30 -> renorm ==
//   softmax over the 30 largest raw logits among valid keys (len >= 1024 >> 30).
// GEMMs (k1,k3): f16 MFMA.  k2: 512 threads (8 waves), 16 rows/block, THREE
// blocks/CU (47 KB LDS, launch_bounds(512,6) -> VGPR<=84, kernel uses ~64).
// Scores: MFMA, fragment-native B layout x2tn (16B/lane coalesced).  Top-k
// EXACT in FOUR key-quarters over scU[16][512]: per-quarter 30th value by
// MSB-first binary search with exact-count early exit (count==30 => up-set of
// unique values IS the top-30); final top-30 of 120 candidates (2/lane).
// Quarter order rotated by rowblock (anti-lockstep).  Batch-per-XCD mapping.

typedef _Float16 h2   __attribute__((ext_vector_type(2)));
typedef _Float16 h4   __attribute__((ext_vector_type(4)));
typedef _Float16 h8   __attribute__((ext_vector_type(8)));
typedef float    f32x4 __attribute__((ext_vector_type(4)));

__device__ __forceinline__ h2 as_h2(float f) {
    union { float f; h2 h; } u; u.f = f; return u.h;
}
__device__ __forceinline__ float packh2(float a, float b) {
    union { h2 h; float f; } u; u.h.x = (_Float16)a; u.h.y = (_Float16)b; return u.f;
}

// ---------------------------------------------------------------------------
// k0: merged transpose-pack of all four weight matrices, fp32 [K][N] -> f16
// [N][K] in 32x32 tiles.
// ---------------------------------------------------------------------------
__global__ __launch_bounds__(256) void k0_pack(
    const float* __restrict__ wg, const float* __restrict__ w1,
    const float* __restrict__ w2, const float* __restrict__ wz,
    _Float16* __restrict__ wT, _Float16* __restrict__ wzT)
{
    __shared__ float tile[32][33];
    const int id = blockIdx.x;
    const float* src; _Float16* dst; int Nd, n0, k0;
    if (id < 256)      { src = wg; dst = wT;            Nd = 512; n0 = (id & 15) * 32;        k0 = (id >> 4) * 32; }
    else if (id < 384) { src = w1; dst = wT + 512*512;  Nd = 256; n0 = ((id-256) & 7) * 32;   k0 = ((id-256) >> 3) * 32; }
    else if (id < 512) { src = w2; dst = wT + 768*512;  Nd = 256; n0 = ((id-384) & 7) * 32;   k0 = ((id-384) >> 3) * 32; }
    else               { src = wz; dst = wzT;           Nd = 512; n0 = ((id-512) & 15) * 32;  k0 = ((id-512) >> 4) * 32; }

    const int t = threadIdx.x;
    const int r = t >> 3, c = (t & 7) * 4;
    *(float4*)&tile[r][c] = *(const float4*)(src + (size_t)(k0 + r) * Nd + n0 + c);
    __syncthreads();
    h4 hv;
    hv.x = (_Float16)tile[c + 0][r];
    hv.y = (_Float16)tile[c + 1][r];
    hv.z = (_Float16)tile[c + 2][r];
    hv.w = (_Float16)tile[c + 3][r];
    *(h4*)(dst + (size_t)(n0 + r) * 512 + k0 + c) = hv;
}

// ---------------------------------------------------------------------------
// k1: MFMA projection GEMM.  BM=64 rows x BN=256 cols, BK=64, 4 waves.
// blockIdx.y = col-block: 0,1 -> x_prime (h2-packed xph), 2 -> x1 (x1p),
// 3 -> x2 (fragment-native x2tn via LDS tile T[ep][key]).
// ---------------------------------------------------------------------------
__global__ __launch_bounds__(256) void k1_mfma(
    const float* __restrict__ x, const _Float16* __restrict__ wT,
    const float* __restrict__ bg, const float* __restrict__ b1,
    const float* __restrict__ b2,
    float* __restrict__ xph, float* __restrict__ x1p, float4* __restrict__ x2tn4)
{
    __shared__ __align__(16) char lds_raw[40960];
    _Float16* Alds = (_Float16*)lds_raw;             // [64][64] f16 = 8 KB
    _Float16* Blds = (_Float16*)(lds_raw + 8192);    // [256][64] f16 = 32 KB

    const int t = threadIdx.x;
    const int m0 = blockIdx.x * 64;
    const int cb = blockIdx.y;
    const int n0 = cb * 256;                         // row base in wT
    const int lane = t & 63, w = t >> 6;
    const int arow = lane & 15, ak = (lane >> 4) * 8;

    f32x4 acc[4][4];
    #pragma unroll
    for (int i = 0; i < 4; ++i)
        #pragma unroll
        for (int j = 0; j < 4; ++j) acc[i][j] = (f32x4){0.f, 0.f, 0.f, 0.f};

    for (int k0 = 0; k0 < 512; k0 += 64) {
        __syncthreads();
        {   // stage A: 64 rows x 64 k fp32 -> f16
            const int r = t >> 2, c0 = (t & 3) * 16;
            const float* src = x + (size_t)(m0 + r) * 512 + k0 + c0;
            #pragma unroll
            for (int hvi = 0; hvi < 2; ++hvi) {
                float4 u0 = *(const float4*)(src + hvi * 8);
                float4 u1 = *(const float4*)(src + hvi * 8 + 4);
                h8 hv;
                hv[0] = (_Float16)u0.x; hv[1] = (_Float16)u0.y;
                hv[2] = (_Float16)u0.z; hv[3] = (_Float16)u0.w;
                hv[4] = (_Float16)u1.x; hv[5] = (_Float16)u1.y;
                hv[6] = (_Float16)u1.z; hv[7] = (_Float16)u1.w;
                *(h8*)(Alds + r * 64 + c0 + hvi * 8) = hv;
            }
        }
        {   // stage B: 256 n-rows x 64 k f16.  8 lanes cover one 128B row.
            #pragma unroll
            for (int i = 0; i < 8; ++i) {
                int idx = t + i * 256;               // 0..2047
                int row = idx >> 3, ch = idx & 7;
                *(float4*)(Blds + row * 64 + ch * 8) =
                    *(const float4*)(wT + (size_t)(n0 + row) * 512 + k0 + ch * 8);
            }
        }
        __syncthreads();

        #pragma unroll
        for (int kk = 0; kk < 2; ++kk) {
            h8 af[4], bf[4];
            #pragma unroll
            for (int rb = 0; rb < 4; ++rb)
                af[rb] = *(const h8*)(Alds + (rb * 16 + arow) * 64 + kk * 32 + ak);
            #pragma unroll
            for (int cf = 0; cf < 4; ++cf)
                bf[cf] = *(const h8*)(Blds + (w * 64 + cf * 16 + arow) * 64 + kk * 32 + ak);
            #pragma unroll
            for (int rb = 0; rb < 4; ++rb)
                #pragma unroll
                for (int cf = 0; cf < 4; ++cf)
                    acc[rb][cf] = __builtin_amdgcn_mfma_f32_16x16x32_f16(
                        af[rb], bf[cf], acc[rb][cf], 0, 0, 0);
        }
    }

    const float* bias = (cb < 2) ? (bg + cb * 256) : (cb == 2 ? b1 : b2);

    if (cb < 3) {
        // pack e-pairs via lane shuffle; even lanes store 4B
        float* dst; int epbase; size_t rstr;
        if (cb < 2) { dst = xph; epbase = cb * 128; rstr = 256; }
        else        { dst = x1p; epbase = 0;        rstr = 128; }
        #pragma unroll
        for (int cf = 0; cf < 4; ++cf) {
            const int c = w * 64 + cf * 16 + arow;
            const float bv = bias[c];
            #pragma unroll
            for (int rb = 0; rb < 4; ++rb) {
                #pragma unroll
                for (int j = 0; j < 4; ++j) {
                    float v = acc[rb][cf][j] + bv;
                    float o = __shfl_xor(v, 1);
                    if ((lane & 1) == 0) {
                        int row = m0 + rb * 16 + (lane >> 4) * 4 + j;
                        dst[(size_t)row * rstr + epbase + (c >> 1)] = packh2(v, o);
                    }
                }
            }
        }
    } else {
        // x2: pack pairs -> LDS tile T[ep][key_local] (stride 68), then emit
        // fragment-native x2tn (coalesced 16B/lane stores).
        __syncthreads();                              // done with Alds/Blds
        float* T = (float*)lds_raw;                   // [128][68] floats = 34816 B
        #pragma unroll
        for (int cf = 0; cf < 4; ++cf) {
            const int c = w * 64 + cf * 16 + arow;
            const float bv = bias[c];
            #pragma unroll
            for (int rb = 0; rb < 4; ++rb) {
                #pragma unroll
                for (int j = 0; j < 4; ++j) {
                    float v = acc[rb][cf][j] + bv;
                    float o = __shfl_xor(v, 1);
                    if ((lane & 1) == 0)
                        T[(c >> 1) * 68 + rb * 16 + (lane >> 4) * 4 + j] = packh2(v, o);
                }
            }
        }
        __syncthreads();
        const int bb = m0 >> 11, j0 = m0 & 2047;      // 4 j-tiles: (j0>>4)+0..3
        #pragma unroll
        for (int g = 0; g < 8; ++g) {
            int slot = t + g * 256;                   // 0..2047
            int jt = slot >> 9;                       // 0..3
            int ks = (slot >> 6) & 7;                 // 0..7
            int l  = slot & 63;
            int eg = l >> 4, jc = l & 15;
            const float* Tp = T + (ks * 16 + eg * 4) * 68 + jt * 16 + jc;
            float4 v;
            v.x = Tp[0]; v.y = Tp[68]; v.z = Tp[136]; v.w = Tp[204];
            x2tn4[(((size_t)bb * 128 + (j0 >> 4) + jt) * 8 + ks) * 64 + l] = v;
        }
    }
}

// ---------------------------------------------------------------------------
// k2: 512 threads (8 waves), 16 rows/block, 3 blocks/CU (47 KB LDS).
// Block mapping: batch = blockIdx.x & 7 (XCD affinity), rowblock = bid >> 3.
// Quarter order rotated by rowblock.  Per key-quarter q (keys [q*512,+512)):
//   Phase A(q): wave w computes keys [q*512+w*64, +64) as 4 tiles x
//     8 k-steps; B fragments = one coalesced float4/lane per (tile,ks)
//     from x2tn -> scU[16][512] u-packed.
//   Phase B(q): wave w rows {2w,2w+1}: 30th value by binary search with
//     exact-count early exit (8 regs/lane); compaction -> cand[row][q*30+..].
// Final: top-30 of 120 candidates (2/lane) + rowmax; unpack; softmax;
// h2-packed gather of x_prime.
// ---------------------------------------------------------------------------
__global__ __launch_bounds__(512, 6) void k2_attn(
    const float* __restrict__ x1p, const float4* __restrict__ x2tn4,
    const float* __restrict__ xph, const int* __restrict__ xlen,
    float* __restrict__ yah)
{
    __shared__ unsigned scU[16][512];             // 32 KB (reused per quarter)
    __shared__ unsigned cand[16][128];            // 8 KB candidates (120 used)
    __shared__ unsigned tkp[16][30];
    __shared__ float    wvs[16][30];
    __shared__ int      tki[16][30];
    __shared__ float    vin[16];
    __shared__ unsigned rowmax[16];
    __shared__ int      cntA[16][4];
    __shared__ int      cntF[16];

    const int t  = threadIdx.x;
    const int b  = blockIdx.x & 7;                // batch-per-XCD affinity
    const int i0 = (blockIdx.x >> 3) * 16;
    const int qfirst = (blockIdx.x >> 3) & 3;     // rotate quarter order
    const int len = xlen[b];
    const int lane = t & 63, wid = t >> 6;        // 8 waves

    #pragma unroll
    for (int i = 0; i < 4; ++i)
        ((unsigned*)cand)[t + i * 512] = 0u;      // 2048 entries
    if (t < 64) cntA[t >> 2][t & 3] = 0;
    if (t < 16) cntF[t] = 0;

    // A fragments (shared across quarters): row = lane&15, k = (lane>>4)*8
    h8 afr[8];
    {
        const int ar = lane & 15;
        const float* x1row = x1p + ((size_t)b * 2048 + i0 + ar) * 128 + (lane >> 4) * 4;
        #pragma unroll
        for (int ks = 0; ks < 8; ++ks)
            afr[ks] = *(const h8*)(x1row + ks * 16);
    }

    const float4* x2b = x2tn4 + ((size_t)b * 128) * 8 * 64 + lane;
    const int jcol  = lane & 15;
    const int rbase = (lane >> 4) * 4;            // C row base

#define LOADT(Q, NT, DST)                                                   \
    {                                                                       \
        const float4* pb_ = x2b + (size_t)(((Q) * 32 + wid * 4 + (NT)) * 8) * 64; \
        _Pragma("unroll")                                                   \
        for (int ks = 0; ks < 8; ++ks)                                      \
            DST[ks] = *(const h8*)(pb_ + ks * 64);                          \
    }

#define MFMAT(Q, NT, SRC)                                                   \
    {                                                                       \
        const int j_ = (Q) * 512 + wid * 64 + (NT) * 16 + jcol;             \
        const int cs_ = wid * 64 + (NT) * 16 + jcol;                        \
        f32x4 acc = (f32x4){0.f, 0.f, 0.f, 0.f};                            \
        _Pragma("unroll")                                                   \
        for (int ks = 0; ks < 8; ++ks)                                      \
            acc = __builtin_amdgcn_mfma_f32_16x16x32_f16(afr[ks], SRC[ks], acc, 0, 0, 0); \
        const unsigned tag = (unsigned)(2047 - j_);                         \
        const bool valid = (j_ < len);                                      \
        _Pragma("unroll")                                                   \
        for (int jj = 0; jj < 4; ++jj) {                                    \
            unsigned bb = __float_as_uint(acc[jj]);                         \
            bb = bb ^ (0x80000000u | (unsigned)((int)bb >> 31));            \
            scU[rbase + jj][cs_] = valid ? ((bb & 0xFFFFF800u) | tag) : 0u; \
        }                                                                   \
    }

    for (int qq = 0; qq < 4; ++qq) {
        const int q = (qfirst + qq) & 3;          // rotated quarter order
        {   // phase A(q): 4 tiles, 2-deep prefetch
            h8 va[8], vb[8];
            LOADT(q, 0, va)
            LOADT(q, 1, vb)
            MFMAT(q, 0, va)  LOADT(q, 2, va)
            MFMAT(q, 1, vb)  LOADT(q, 3, vb)
            MFMAT(q, 2, va)
            MFMAT(q, 3, vb)
        }
        __syncthreads();

        // phase B(q): wave wid owns rows {2*wid, 2*wid+1}
        #pragma unroll
        for (int rr = 0; rr < 2; ++rr) {
            const int row = wid * 2 + rr;
            unsigned u0[8];
            #pragma unroll
            for (int c = 0; c < 2; ++c)
                *(uint4*)&u0[c * 4] = *(const uint4*)&scU[row][lane * 4 + c * 256];

            unsigned P = 0u;
            for (int bit = 31; bit >= 0; --bit) {
                const unsigned cd = P | (1u << bit);
                int cnt = 0;
                #pragma unroll
                for (int qv = 0; qv < 8; ++qv)
                    cnt += (int)__popcll(__ballot(u0[qv] >= cd));
                if (cnt >= 30) {
                    P = cd;
                    if (cnt == 30) break;         // exact: {v>=P} IS the top-30
                }
            }
            #pragma unroll
            for (int qv = 0; qv < 8; ++qv) {
                if (u0[qv] >= P && u0[qv] != 0u) {
                    int s = atomicAdd(&cntA[row][q], 1);
                    cand[row][q * 30 + s] = u0[qv];
                }
            }
        }
        __syncthreads();                          // also guards scU reuse
    }
#undef LOADT
#undef MFMAT

    // ---- final: top-30 of 120 candidates + rowmax; wave wid rows {2w,2w+1} ----
    #pragma unroll
    for (int rr = 0; rr < 2; ++rr) {
        const int row = wid * 2 + rr;
        unsigned v0 = (lane < 120) ? cand[row][lane] : 0u;          // lanes 0..59 used
        unsigned v1 = (lane + 64 < 120) ? cand[row][lane + 64] : 0u;
        unsigned lm = v0 > v1 ? v0 : v1;
        #pragma unroll
        for (int off = 32; off > 0; off >>= 1) {
            unsigned o = (unsigned)__shfl_xor((int)lm, off);
            lm = lm > o ? lm : o;
        }
        if (lane == 0) rowmax[row] = lm;

        unsigned P = 0u;
        for (int bit = 31; bit >= 0; --bit) {
            const unsigned cd = P | (1u << bit);
            int cnt = (int)__popcll(__ballot(v0 >= cd))
                    + (int)__popcll(__ballot(v1 >= cd));
            if (cnt >= 30) {
                P = cd;
                if (cnt == 30) break;             // exact early exit
            }
        }
        if (v0 >= P && v0 != 0u) { int s = atomicAdd(&cntF[row], 1); tkp[row][s] = v0; }
        if (v1 >= P && v1 != 0u) { int s = atomicAdd(&cntF[row], 1); tkp[row][s] = v1; }
    }
    __syncthreads();

    // ---- unpack + per-row softmax weights (base = rowmax) ----
    {
        const int r = t >> 5, k = t & 31;         // 32 threads per row
        if (k < 30) {
            unsigned u = tkp[r][k];
            unsigned m0 = rowmax[r] & 0xFFFFF800u;
            unsigned ub = u & 0xFFFFF800u;
            unsigned bb0 = (m0 & 0x80000000u) ? (m0 ^ 0x80000000u) : ~m0;
            unsigned bbk = (ub & 0x80000000u) ? (ub ^ 0x80000000u) : ~ub;
            float s0 = __uint_as_float(bb0);
            float sk = __uint_as_float(bbk);
            wvs[r][k] = __expf(sk - s0);
            tki[r][k] = 2047 - (int)(u & 0x7FFu);
        }
    }
    __syncthreads();
    if (t < 16) {
        float s = 0.f;
        #pragma unroll
        for (int k = 0; k < 30; ++k) s += wvs[t][k];
        vin[t] = 1.f / s;
    }
    __syncthreads();

    // ---- phase C: gather of h2-packed x_prime; 256 threads per 8 rows ----
    const int g  = t >> 8;                        // 0..1 -> rows g*8..g*8+8
    const int hp = t & 255;                       // h2-pair index
    for (int r = g * 8; r < g * 8 + 8; ++r) {
        float y0 = 0.f, y1 = 0.f;
        #pragma unroll
        for (int k = 0; k < 30; ++k) {
            int j = tki[r][k];
            float wv = wvs[r][k];
            h2 u = as_h2(xph[((size_t)b * 2048 + j) * 256 + hp]);
            y0 = fmaf(wv, (float)u.x, y0);
            y1 = fmaf(wv, (float)u.y, y1);
        }
        const float inv = vin[r];
        yah[((size_t)b * 2048 + i0 + r) * 256 + hp] = packh2(y0 * inv, y1 * inv);
    }
}

// ---------------------------------------------------------------------------
// k3: out = x + yah @ wzT^T + bz.  MFMA, BM=64, BN=256 (2 col-blocks), BK=64.
// ---------------------------------------------------------------------------
__global__ __launch_bounds__(256) void k3_mfma(
    const float* __restrict__ yah, const _Float16* __restrict__ wzT,
    const float* __restrict__ bz, const float* __restrict__ x,
    float* __restrict__ out)
{
    __shared__ __align__(16) char lds_raw[40960];
    _Float16* Alds = (_Float16*)lds_raw;             // [64][64]
    _Float16* Blds = (_Float16*)(lds_raw + 8192);    // [256][64]

    const int t = threadIdx.x;
    const int m0 = blockIdx.x * 64;
    const int n0 = blockIdx.y * 256;
    const int lane = t & 63, w = t >> 6;
    const int arow = lane & 15, ak = (lane >> 4) * 8;

    f32x4 acc[4][4];
    #pragma unroll
    for (int i = 0; i < 4; ++i)
        #pragma unroll
        for (int j = 0; j < 4; ++j) acc[i][j] = (f32x4){0.f, 0.f, 0.f, 0.f};

    for (int k0 = 0; k0 < 512; k0 += 64) {
        __syncthreads();
        {   // stage A: h2-packed rows, pure copy. 64 rows x 32 floats
            const int r = t >> 2, c0 = (t & 3) * 8;   // float chunk
            const float4* src = (const float4*)(yah + (size_t)(m0 + r) * 256 + k0 / 2 + c0);
            float4* dst = (float4*)(Alds + r * 64 + c0 * 2);
            dst[0] = src[0]; dst[1] = src[1];
        }
        {   // stage B: 256 n-rows x 64 k f16.  8 lanes cover one 128B row.
            #pragma unroll
            for (int i = 0; i < 8; ++i) {
                int idx = t + i * 256;               // 0..2047
                int row = idx >> 3, ch = idx & 7;
                *(float4*)(Blds + row * 64 + ch * 8) =
                    *(const float4*)(wzT + (size_t)(n0 + row) * 512 + k0 + ch * 8);
            }
        }
        __syncthreads();

        #pragma unroll
        for (int kk = 0; kk < 2; ++kk) {
            h8 af[4], bf[4];
            #pragma unroll
            for (int rb = 0; rb < 4; ++rb)
                af[rb] = *(const h8*)(Alds + (rb * 16 + arow) * 64 + kk * 32 + ak);
            #pragma unroll
            for (int cf = 0; cf < 4; ++cf)
                bf[cf] = *(const h8*)(Blds + (w * 64 + cf * 16 + arow) * 64 + kk * 32 + ak);
            #pragma unroll
            for (int rb = 0; rb < 4; ++rb)
                #pragma unroll
                for (int cf = 0; cf < 4; ++cf)
                    acc[rb][cf] = __builtin_amdgcn_mfma_f32_16x16x32_f16(
                        af[rb], bf[cf], acc[rb][cf], 0, 0, 0);
        }
    }

    #pragma unroll
    for (int cf = 0; cf < 4; ++cf) {
        const int c = n0 + w * 64 + cf * 16 + arow;
        const float bv = bz[c];
        #pragma unroll
        for (int rb = 0; rb < 4; ++rb) {
            #pragma unroll
            for (int j = 0; j < 4; ++j) {
                int row = m0 + rb * 16 + (lane >> 4) * 4 + j;
                out[(size_t)row * 512 + c] =
                    acc[rb][cf][j] + bv + x[(size_t)row * 512 + c];
            }
        }
    }
}

extern "C" void kernel_launch(void* const* d_in, const int* in_sizes, int n_in,
                              void* d_out, int out_size, void* d_ws, size_t ws_size,
                              hipStream_t stream)
{
    (void)in_sizes; (void)n_in; (void)out_size; (void)ws_size;

    const float* x   = (const float*)d_in[0];
    const float* wg  = (const float*)d_in[1];
    const float* bg  = (const float*)d_in[2];
    const float* w1  = (const float*)d_in[3];
    const float* b1  = (const float*)d_in[4];
    const float* w2  = (const float*)d_in[5];
    const float* b2  = (const float*)d_in[6];
    const float* wzw = (const float*)d_in[7];
    const float* wzb = (const float*)d_in[8];
    const int* xlen  = (const int*)d_in[9];
    float* outp      = (float*)d_out;

    char* ws = (char*)d_ws;
    _Float16* wT   = (_Float16*)(ws);                       // 1 MiB [1024][512] f16
    _Float16* wzT  = (_Float16*)(ws + 1u * 1024 * 1024);    // 0.5 MiB [512][512] f16
    float* x1pw    = (float*)(ws +  2u * 1024 * 1024);      // 8 MiB [16384][128] h2
    float4* x2tnw  = (float4*)(ws + 10u * 1024 * 1024);     // 8 MiB [8][128][8][64] float4
    float* xphw    = (float*)(ws + 18u * 1024 * 1024);      // 16 MiB [16384][256] h2
    float* yahw    = (float*)(ws + 34u * 1024 * 1024);      // 16 MiB [16384][256] h2

    hipLaunchKernelGGL(k0_pack, dim3(768), dim3(256), 0, stream,
                       wg, w1, w2, wzw, wT, wzT);
    hipLaunchKernelGGL(k1_mfma, dim3(256, 4), dim3(256), 0, stream,
                       x, wT, bg, b1, b2, xphw, x1pw, x2tnw);
    hipLaunchKernelGGL(k2_attn, dim3(1024), dim3(512), 0, stream,
                       x1pw, x2tnw, xphw, xlen, yahw);
    hipLaunchKernelGGL(k3_mfma, dim3(256, 2), dim3(256), 0, stream,
                       yahw, wzT, wzb, x, outp);
}

// Round 23
// 212.992 us; speedup vs baseline: 1.0721x; 1.0721x over previous
//
#include <hip/hip_runtime.h>

// B=8, L=2048, D=512, H=512, E=256, K=30.  fp32 I/O, x_lengths int32.
// Identity: softmax -> key-mask -> renorm -> top-30 -> renorm ==
//   softmax over the 30 largest raw logits among valid keys (len >= 1024 >> 30).
// GEMMs (k1,k3): f16 MFMA.  k2: 512 threads (8 waves), 16 rows/block, 3
// blocks/CU by LDS (47 KB) with NATURAL register budget (launch_bounds(512,4);
// r22's (512,6) squeezed VGPR to 40 and spilled).  Scores: MFMA,
// fragment-native B layout x2tn.  Top-k EXACT in four key-quarters over
// scU[16][512]: per-quarter 30th value by MSB-first binary search with
// exact-count early exit; final top-30 of 120 candidates (2/lane).
// Quarter order rotated by rowblock.  Batch-per-XCD mapping.

typedef _Float16 h2   __attribute__((ext_vector_type(2)));
typedef _Float16 h4   __attribute__((ext_vector_type(4)));
typedef _Float16 h8   __attribute__((ext_vector_type(8)));
typedef float    f32x4 __attribute__((ext_vector_type(4)));

__device__ __forceinline__ h2 as_h2(float f) {
    union { float f; h2 h; } u; u.f = f; return u.h;
}
__device__ __forceinline__ float packh2(float a, float b) {
    union { h2 h; float f; } u; u.h.x = (_Float16)a; u.h.y = (_Float16)b; return u.f;
}

// ---------------------------------------------------------------------------
// k0: merged transpose-pack of all four weight matrices, fp32 [K][N] -> f16
// [N][K] in 32x32 tiles.
// ---------------------------------------------------------------------------
__global__ __launch_bounds__(256) void k0_pack(
    const float* __restrict__ wg, const float* __restrict__ w1,
    const float* __restrict__ w2, const float* __restrict__ wz,
    _Float16* __restrict__ wT, _Float16* __restrict__ wzT)
{
    __shared__ float tile[32][33];
    const int id = blockIdx.x;
    const float* src; _Float16* dst; int Nd, n0, k0;
    if (id < 256)      { src = wg; dst = wT;            Nd = 512; n0 = (id & 15) * 32;        k0 = (id >> 4) * 32; }
    else if (id < 384) { src = w1; dst = wT + 512*512;  Nd = 256; n0 = ((id-256) & 7) * 32;   k0 = ((id-256) >> 3) * 32; }
    else if (id < 512) { src = w2; dst = wT + 768*512;  Nd = 256; n0 = ((id-384) & 7) * 32;   k0 = ((id-384) >> 3) * 32; }
    else               { src = wz; dst = wzT;           Nd = 512; n0 = ((id-512) & 15) * 32;  k0 = ((id-512) >> 4) * 32; }

    const int t = threadIdx.x;
    const int r = t >> 3, c = (t & 7) * 4;
    *(float4*)&tile[r][c] = *(const float4*)(src + (size_t)(k0 + r) * Nd + n0 + c);
    __syncthreads();
    h4 hv;
    hv.x = (_Float16)tile[c + 0][r];
    hv.y = (_Float16)tile[c + 1][r];
    hv.z = (_Float16)tile[c + 2][r];
    hv.w = (_Float16)tile[c + 3][r];
    *(h4*)(dst + (size_t)(n0 + r) * 512 + k0 + c) = hv;
}

// ---------------------------------------------------------------------------
// k1: MFMA projection GEMM.  BM=64 rows x BN=256 cols, BK=64, 4 waves.
// blockIdx.y = col-block: 0,1 -> x_prime (h2-packed xph), 2 -> x1 (x1p),
// 3 -> x2 (fragment-native x2tn via LDS tile T[ep][key]).
// ---------------------------------------------------------------------------
__global__ __launch_bounds__(256) void k1_mfma(
    const float* __restrict__ x, const _Float16* __restrict__ wT,
    const float* __restrict__ bg, const float* __restrict__ b1,
    const float* __restrict__ b2,
    float* __restrict__ xph, float* __restrict__ x1p, float4* __restrict__ x2tn4)
{
    __shared__ __align__(16) char lds_raw[40960];
    _Float16* Alds = (_Float16*)lds_raw;             // [64][64] f16 = 8 KB
    _Float16* Blds = (_Float16*)(lds_raw + 8192);    // [256][64] f16 = 32 KB

    const int t = threadIdx.x;
    const int m0 = blockIdx.x * 64;
    const int cb = blockIdx.y;
    const int n0 = cb * 256;                         // row base in wT
    const int lane = t & 63, w = t >> 6;
    const int arow = lane & 15, ak = (lane >> 4) * 8;

    f32x4 acc[4][4];
    #pragma unroll
    for (int i = 0; i < 4; ++i)
        #pragma unroll
        for (int j = 0; j < 4; ++j) acc[i][j] = (f32x4){0.f, 0.f, 0.f, 0.f};

    for (int k0 = 0; k0 < 512; k0 += 64) {
        __syncthreads();
        {   // stage A: 64 rows x 64 k fp32 -> f16
            const int r = t >> 2, c0 = (t & 3) * 16;
            const float* src = x + (size_t)(m0 + r) * 512 + k0 + c0;
            #pragma unroll
            for (int hvi = 0; hvi < 2; ++hvi) {
                float4 u0 = *(const float4*)(src + hvi * 8);
                float4 u1 = *(const float4*)(src + hvi * 8 + 4);
                h8 hv;
                hv[0] = (_Float16)u0.x; hv[1] = (_Float16)u0.y;
                hv[2] = (_Float16)u0.z; hv[3] = (_Float16)u0.w;
                hv[4] = (_Float16)u1.x; hv[5] = (_Float16)u1.y;
                hv[6] = (_Float16)u1.z; hv[7] = (_Float16)u1.w;
                *(h8*)(Alds + r * 64 + c0 + hvi * 8) = hv;
            }
        }
        {   // stage B: 256 n-rows x 64 k f16.  8 lanes cover one 128B row.
            #pragma unroll
            for (int i = 0; i < 8; ++i) {
                int idx = t + i * 256;               // 0..2047
                int row = idx >> 3, ch = idx & 7;
                *(float4*)(Blds + row * 64 + ch * 8) =
                    *(const float4*)(wT + (size_t)(n0 + row) * 512 + k0 + ch * 8);
            }
        }
        __syncthreads();

        #pragma unroll
        for (int kk = 0; kk < 2; ++kk) {
            h8 af[4], bf[4];
            #pragma unroll
            for (int rb = 0; rb < 4; ++rb)
                af[rb] = *(const h8*)(Alds + (rb * 16 + arow) * 64 + kk * 32 + ak);
            #pragma unroll
            for (int cf = 0; cf < 4; ++cf)
                bf[cf] = *(const h8*)(Blds + (w * 64 + cf * 16 + arow) * 64 + kk * 32 + ak);
            #pragma unroll
            for (int rb = 0; rb < 4; ++rb)
                #pragma unroll
                for (int cf = 0; cf < 4; ++cf)
                    acc[rb][cf] = __builtin_amdgcn_mfma_f32_16x16x32_f16(
                        af[rb], bf[cf], acc[rb][cf], 0, 0, 0);
        }
    }

    const float* bias = (cb < 2) ? (bg + cb * 256) : (cb == 2 ? b1 : b2);

    if (cb < 3) {
        // pack e-pairs via lane shuffle; even lanes store 4B
        float* dst; int epbase; size_t rstr;
        if (cb < 2) { dst = xph; epbase = cb * 128; rstr = 256; }
        else        { dst = x1p; epbase = 0;        rstr = 128; }
        #pragma unroll
        for (int cf = 0; cf < 4; ++cf) {
            const int c = w * 64 + cf * 16 + arow;
            const float bv = bias[c];
            #pragma unroll
            for (int rb = 0; rb < 4; ++rb) {
                #pragma unroll
                for (int j = 0; j < 4; ++j) {
                    float v = acc[rb][cf][j] + bv;
                    float o = __shfl_xor(v, 1);
                    if ((lane & 1) == 0) {
                        int row = m0 + rb * 16 + (lane >> 4) * 4 + j;
                        dst[(size_t)row * rstr + epbase + (c >> 1)] = packh2(v, o);
                    }
                }
            }
        }
    } else {
        // x2: pack pairs -> LDS tile T[ep][key_local] (stride 68), then emit
        // fragment-native x2tn (coalesced 16B/lane stores).
        __syncthreads();                              // done with Alds/Blds
        float* T = (float*)lds_raw;                   // [128][68] floats = 34816 B
        #pragma unroll
        for (int cf = 0; cf < 4; ++cf) {
            const int c = w * 64 + cf * 16 + arow;
            const float bv = bias[c];
            #pragma unroll
            for (int rb = 0; rb < 4; ++rb) {
                #pragma unroll
                for (int j = 0; j < 4; ++j) {
                    float v = acc[rb][cf][j] + bv;
                    float o = __shfl_xor(v, 1);
                    if ((lane & 1) == 0)
                        T[(c >> 1) * 68 + rb * 16 + (lane >> 4) * 4 + j] = packh2(v, o);
                }
            }
        }
        __syncthreads();
        const int bb = m0 >> 11, j0 = m0 & 2047;      // 4 j-tiles: (j0>>4)+0..3
        #pragma unroll
        for (int g = 0; g < 8; ++g) {
            int slot = t + g * 256;                   // 0..2047
            int jt = slot >> 9;                       // 0..3
            int ks = (slot >> 6) & 7;                 // 0..7
            int l  = slot & 63;
            int eg = l >> 4, jc = l & 15;
            const float* Tp = T + (ks * 16 + eg * 4) * 68 + jt * 16 + jc;
            float4 v;
            v.x = Tp[0]; v.y = Tp[68]; v.z = Tp[136]; v.w = Tp[204];
            x2tn4[(((size_t)bb * 128 + (j0 >> 4) + jt) * 8 + ks) * 64 + l] = v;
        }
    }
}

// ---------------------------------------------------------------------------
// k2: 512 threads (8 waves), 16 rows/block, 3 blocks/CU by LDS (47 KB).
// Natural register budget (launch_bounds(512,4) — no allocator squeeze).
// Block mapping: batch = blockIdx.x & 7 (XCD affinity), rowblock = bid >> 3.
// Quarter order rotated by rowblock.  Per key-quarter q (keys [q*512,+512)):
//   Phase A(q): wave w computes keys [q*512+w*64, +64) as 4 tiles x
//     8 k-steps; B fragments = one coalesced float4/lane per (tile,ks)
//     from x2tn -> scU[16][512] u-packed.
//   Phase B(q): wave w rows {2w,2w+1}: 30th value by binary search with
//     exact-count early exit (8 regs/lane); compaction -> cand[row][q*30+..].
// Final: top-30 of 120 candidates (2/lane) + rowmax; unpack; softmax;
// h2-packed gather of x_prime.
// ---------------------------------------------------------------------------
__global__ __launch_bounds__(512, 4) void k2_attn(
    const float* __restrict__ x1p, const float4* __restrict__ x2tn4,
    const float* __restrict__ xph, const int* __restrict__ xlen,
    float* __restrict__ yah)
{
    __shared__ unsigned scU[16][512];             // 32 KB (reused per quarter)
    __shared__ unsigned cand[16][128];            // 8 KB candidates (120 used)
    __shared__ unsigned tkp[16][30];
    __shared__ float    wvs[16][30];
    __shared__ int      tki[16][30];
    __shared__ float    vin[16];
    __shared__ unsigned rowmax[16];
    __shared__ int      cntA[16][4];
    __shared__ int      cntF[16];

    const int t  = threadIdx.x;
    const int b  = blockIdx.x & 7;                // batch-per-XCD affinity
    const int i0 = (blockIdx.x >> 3) * 16;
    const int qfirst = (blockIdx.x >> 3) & 3;     // rotate quarter order
    const int len = xlen[b];
    const int lane = t & 63, wid = t >> 6;        // 8 waves

    #pragma unroll
    for (int i = 0; i < 4; ++i)
        ((unsigned*)cand)[t + i * 512] = 0u;      // 2048 entries
    if (t < 64) cntA[t >> 2][t & 3] = 0;
    if (t < 16) cntF[t] = 0;

    // A fragments (shared across quarters): row = lane&15, k = (lane>>4)*8
    h8 afr[8];
    {
        const int ar = lane & 15;
        const float* x1row = x1p + ((size_t)b * 2048 + i0 + ar) * 128 + (lane >> 4) * 4;
        #pragma unroll
        for (int ks = 0; ks < 8; ++ks)
            afr[ks] = *(const h8*)(x1row + ks * 16);
    }

    const float4* x2b = x2tn4 + ((size_t)b * 128) * 8 * 64 + lane;
    const int jcol  = lane & 15;
    const int rbase = (lane >> 4) * 4;            // C row base

#define LOADT(Q, NT, DST)                                                   \
    {                                                                       \
        const float4* pb_ = x2b + (size_t)(((Q) * 32 + wid * 4 + (NT)) * 8) * 64; \
        _Pragma("unroll")                                                   \
        for (int ks = 0; ks < 8; ++ks)                                      \
            DST[ks] = *(const h8*)(pb_ + ks * 64);                          \
    }

#define MFMAT(Q, NT, SRC)                                                   \
    {                                                                       \
        const int j_ = (Q) * 512 + wid * 64 + (NT) * 16 + jcol;             \
        const int cs_ = wid * 64 + (NT) * 16 + jcol;                        \
        f32x4 acc = (f32x4){0.f, 0.f, 0.f, 0.f};                            \
        _Pragma("unroll")                                                   \
        for (int ks = 0; ks < 8; ++ks)                                      \
            acc = __builtin_amdgcn_mfma_f32_16x16x32_f16(afr[ks], SRC[ks], acc, 0, 0, 0); \
        const unsigned tag = (unsigned)(2047 - j_);                         \
        const bool valid = (j_ < len);                                      \
        _Pragma("unroll")                                                   \
        for (int jj = 0; jj < 4; ++jj) {                                    \
            unsigned bb = __float_as_uint(acc[jj]);                         \
            bb = bb ^ (0x80000000u | (unsigned)((int)bb >> 31));            \
            scU[rbase + jj][cs_] = valid ? ((bb & 0xFFFFF800u) | tag) : 0u; \
        }                                                                   \
    }

    for (int qq = 0; qq < 4; ++qq) {
        const int q = (qfirst + qq) & 3;          // rotated quarter order
        {   // phase A(q): 4 tiles, 2-deep prefetch
            h8 va[8], vb[8];
            LOADT(q, 0, va)
            LOADT(q, 1, vb)
            MFMAT(q, 0, va)  LOADT(q, 2, va)
            MFMAT(q, 1, vb)  LOADT(q, 3, vb)
            MFMAT(q, 2, va)
            MFMAT(q, 3, vb)
        }
        __syncthreads();

        // phase B(q): wave wid owns rows {2*wid, 2*wid+1}
        #pragma unroll
        for (int rr = 0; rr < 2; ++rr) {
            const int row = wid * 2 + rr;
            unsigned u0[8];
            #pragma unroll
            for (int c = 0; c < 2; ++c)
                *(uint4*)&u0[c * 4] = *(const uint4*)&scU[row][lane * 4 + c * 256];

            unsigned P = 0u;
            for (int bit = 31; bit >= 0; --bit) {
                const unsigned cd = P | (1u << bit);
                int cnt = 0;
                #pragma unroll
                for (int qv = 0; qv < 8; ++qv)
                    cnt += (int)__popcll(__ballot(u0[qv] >= cd));
                if (cnt >= 30) {
                    P = cd;
                    if (cnt == 30) break;         // exact: {v>=P} IS the top-30
                }
            }
            #pragma unroll
            for (int qv = 0; qv < 8; ++qv) {
                if (u0[qv] >= P && u0[qv] != 0u) {
                    int s = atomicAdd(&cntA[row][q], 1);
                    cand[row][q * 30 + s] = u0[qv];
                }
            }
        }
        __syncthreads();                          // also guards scU reuse
    }
#undef LOADT
#undef MFMAT

    // ---- final: top-30 of 120 candidates + rowmax; wave wid rows {2w,2w+1} ----
    #pragma unroll
    for (int rr = 0; rr < 2; ++rr) {
        const int row = wid * 2 + rr;
        unsigned v0 = (lane < 120) ? cand[row][lane] : 0u;
        unsigned v1 = (lane + 64 < 120) ? cand[row][lane + 64] : 0u;
        unsigned lm = v0 > v1 ? v0 : v1;
        #pragma unroll
        for (int off = 32; off > 0; off >>= 1) {
            unsigned o = (unsigned)__shfl_xor((int)lm, off);
            lm = lm > o ? lm : o;
        }
        if (lane == 0) rowmax[row] = lm;

        unsigned P = 0u;
        for (int bit = 31; bit >= 0; --bit) {
            const unsigned cd = P | (1u << bit);
            int cnt = (int)__popcll(__ballot(v0 >= cd))
                    + (int)__popcll(__ballot(v1 >= cd));
            if (cnt >= 30) {
                P = cd;
                if (cnt == 30) break;             // exact early exit
            }
        }
        if (v0 >= P && v0 != 0u) { int s = atomicAdd(&cntF[row], 1); tkp[row][s] = v0; }
        if (v1 >= P && v1 != 0u) { int s = atomicAdd(&cntF[row], 1); tkp[row][s] = v1; }
    }
    __syncthreads();

    // ---- unpack + per-row softmax weights (base = rowmax) ----
    {
        const int r = t >> 5, k = t & 31;         // 32 threads per row
        if (k < 30) {
            unsigned u = tkp[r][k];
            unsigned m0 = rowmax[r] & 0xFFFFF800u;
            unsigned ub = u & 0xFFFFF800u;
            unsigned bb0 = (m0 & 0x80000000u) ? (m0 ^ 0x80000000u) : ~m0;
            unsigned bbk = (ub & 0x80000000u) ? (ub ^ 0x80000000u) : ~ub;
            float s0 = __uint_as_float(bb0);
            float sk = __uint_as_float(bbk);
            wvs[r][k] = __expf(sk - s0);
            tki[r][k] = 2047 - (int)(u & 0x7FFu);
        }
    }
    __syncthreads();
    if (t < 16) {
        float s = 0.f;
        #pragma unroll
        for (int k = 0; k < 30; ++k) s += wvs[t][k];
        vin[t] = 1.f / s;
    }
    __syncthreads();

    // ---- phase C: gather of h2-packed x_prime; 256 threads per 8 rows ----
    const int g  = t >> 8;                        // 0..1 -> rows g*8..g*8+8
    const int hp = t & 255;                       // h2-pair index
    for (int r = g * 8; r < g * 8 + 8; ++r) {
        float y0 = 0.f, y1 = 0.f;
        #pragma unroll
        for (int k = 0; k < 30; ++k) {
            int j = tki[r][k];
            float wv = wvs[r][k];
            h2 u = as_h2(xph[((size_t)b * 2048 + j) * 256 + hp]);
            y0 = fmaf(wv, (float)u.x, y0);
            y1 = fmaf(wv, (float)u.y, y1);
        }
        const float inv = vin[r];
        yah[((size_t)b * 2048 + i0 + r) * 256 + hp] = packh2(y0 * inv, y1 * inv);
    }
}

// ---------------------------------------------------------------------------
// k3: out = x + yah @ wzT^T + bz.  MFMA, BM=64, BN=256 (2 col-blocks), BK=64.
// ---------------------------------------------------------------------------
__global__ __launch_bounds__(256) void k3_mfma(
    const float* __restrict__ yah, const _Float16* __restrict__ wzT,
    const float* __restrict__ bz, const float* __restrict__ x,
    float* __restrict__ out)
{
    __shared__ __align__(16) char lds_raw[40960];
    _Float16* Alds = (_Float16*)lds_raw;             // [64][64]
    _Float16* Blds = (_Float16*)(lds_raw + 8192);    // [256][64]

    const int t = threadIdx.x;
    const int m0 = blockIdx.x * 64;
    const int n0 = blockIdx.y * 256;
    const int lane = t & 63, w = t >> 6;
    const int arow = lane & 15, ak = (lane >> 4) * 8;

    f32x4 acc[4][4];
    #pragma unroll
    for (int i = 0; i < 4; ++i)
        #pragma unroll
        for (int j = 0; j < 4; ++j) acc[i][j] = (f32x4){0.f, 0.f, 0.f, 0.f};

    for (int k0 = 0; k0 < 512; k0 += 64) {
        __syncthreads();
        {   // stage A: h2-packed rows, pure copy. 64 rows x 32 floats
            const int r = t >> 2, c0 = (t & 3) * 8;   // float chunk
            const float4* src = (const float4*)(yah + (size_t)(m0 + r) * 256 + k0 / 2 + c0);
            float4* dst = (float4*)(Alds + r * 64 + c0 * 2);
            dst[0] = src[0]; dst[1] = src[1];
        }
        {   // stage B: 256 n-rows x 64 k f16.  8 lanes cover one 128B row.
            #pragma unroll
            for (int i = 0; i < 8; ++i) {
                int idx = t + i * 256;               // 0..2047
                int row = idx >> 3, ch = idx & 7;
                *(float4*)(Blds + row * 64 + ch * 8) =
                    *(const float4*)(wzT + (size_t)(n0 + row) * 512 + k0 + ch * 8);
            }
        }
        __syncthreads();

        #pragma unroll
        for (int kk = 0; kk < 2; ++kk) {
            h8 af[4], bf[4];
            #pragma unroll
            for (int rb = 0; rb < 4; ++rb)
                af[rb] = *(const h8*)(Alds + (rb * 16 + arow) * 64 + kk * 32 + ak);
            #pragma unroll
            for (int cf = 0; cf < 4; ++cf)
                bf[cf] = *(const h8*)(Blds + (w * 64 + cf * 16 + arow) * 64 + kk * 32 + ak);
            #pragma unroll
            for (int rb = 0; rb < 4; ++rb)
                #pragma unroll
                for (int cf = 0; cf < 4; ++cf)
                    acc[rb][cf] = __builtin_amdgcn_mfma_f32_16x16x32_f16(
                        af[rb], bf[cf], acc[rb][cf], 0, 0, 0);
        }
    }

    #pragma unroll
    for (int cf = 0; cf < 4; ++cf) {
        const int c = n0 + w * 64 + cf * 16 + arow;
        const float bv = bz[c];
        #pragma unroll
        for (int rb = 0; rb < 4; ++rb) {
            #pragma unroll
            for (int j = 0; j < 4; ++j) {
                int row = m0 + rb * 16 + (lane >> 4) * 4 + j;
                out[(size_t)row * 512 + c] =
                    acc[rb][cf][j] + bv + x[(size_t)row * 512 + c];
            }
        }
    }
}

extern "C" void kernel_launch(void* const* d_in, const int* in_sizes, int n_in,
                              void* d_out, int out_size, void* d_ws, size_t ws_size,
                              hipStream_t stream)
{
    (void)in_sizes; (void)n_in; (void)out_size; (void)ws_size;

    const float* x   = (const float*)d_in[0];
    const float* wg  = (const float*)d_in[1];
    const float* bg  = (const float*)d_in[2];
    const float* w1  = (const float*)d_in[3];
    const float* b1  = (const float*)d_in[4];
    const float* w2  = (const float*)d_in[5];
    const float* b2  = (const float*)d_in[6];
    const float* wzw = (const float*)d_in[7];
    const float* wzb = (const float*)d_in[8];
    const int* xlen  = (const int*)d_in[9];
    float* outp      = (float*)d_out;

    char* ws = (char*)d_ws;
    _Float16* wT   = (_Float16*)(ws);                       // 1 MiB [1024][512] f16
    _Float16* wzT  = (_Float16*)(ws + 1u * 1024 * 1024);    // 0.5 MiB [512][512] f16
    float* x1pw    = (float*)(ws +  2u * 1024 * 1024);      // 8 MiB [16384][128] h2
    float4* x2tnw  = (float4*)(ws + 10u * 1024 * 1024);     // 8 MiB [8][128][8][64] float4
    float* xphw    = (float*)(ws + 18u * 1024 * 1024);      // 16 MiB [16384][256] h2
    float* yahw    = (float*)(ws + 34u * 1024 * 1024);      // 16 MiB [16384][256] h2

    hipLaunchKernelGGL(k0_pack, dim3(768), dim3(256), 0, stream,
                       wg, w1, w2, wzw, wT, wzT);
    hipLaunchKernelGGL(k1_mfma, dim3(256, 4), dim3(256), 0, stream,
                       x, wT, bg, b1, b2, xphw, x1pw, x2tnw);
    hipLaunchKernelGGL(k2_attn, dim3(1024), dim3(512), 0, stream,
                       x1pw, x2tnw, xphw, xlen, yahw);
    hipLaunchKernelGGL(k3_mfma, dim3(256, 2), dim3(256), 0, stream,
                       yahw, wzT, wzb, x, outp);
}

// Round 24
// 202.963 us; speedup vs baseline: 1.1251x; 1.0494x over previous
//
#include <hip/hip_runtime.h>

// B=8, L=2048, D=512, H=512, E=256, K=30.  fp32 I/O, x_lengths int32.
// Identity: softmax -> key-mask -> renorm -> top-30 -> renorm ==
//   softmax over the 30 largest raw logits among valid keys (len >= 1024 >> 30).
// GEMMs (k1,k3): f16 MFMA.  k2: 512 threads (8 waves), 16 rows/block, 2
// blocks/CU (74 KB LDS).  Scores: MFMA with fragment-native B layout x2tn
// (16B/lane coalesced).  Top-k EXACT in two key-halves; 30th value by
// MSB-first binary search with EARLY EXIT when count==30 (same survivor set:
// an up-set of unique values with exactly 30 members IS the top-30).
// Half order staggered by rowblock parity (anti-lockstep for the 2 co-resident
// blocks).  Final top-30 of 60 candidates.  Batch-per-XCD mapping.
// k0 = single merged weight-pack launch.   [round-21 best configuration]

typedef _Float16 h2   __attribute__((ext_vector_type(2)));
typedef _Float16 h4   __attribute__((ext_vector_type(4)));
typedef _Float16 h8   __attribute__((ext_vector_type(8)));
typedef float    f32x4 __attribute__((ext_vector_type(4)));

__device__ __forceinline__ h2 as_h2(float f) {
    union { float f; h2 h; } u; u.f = f; return u.h;
}
__device__ __forceinline__ float packh2(float a, float b) {
    union { h2 h; float f; } u; u.h.x = (_Float16)a; u.h.y = (_Float16)b; return u.f;
}

// ---------------------------------------------------------------------------
// k0: merged transpose-pack of all four weight matrices, fp32 [K][N] -> f16
// [N][K] in 32x32 tiles.
// ---------------------------------------------------------------------------
__global__ __launch_bounds__(256) void k0_pack(
    const float* __restrict__ wg, const float* __restrict__ w1,
    const float* __restrict__ w2, const float* __restrict__ wz,
    _Float16* __restrict__ wT, _Float16* __restrict__ wzT)
{
    __shared__ float tile[32][33];
    const int id = blockIdx.x;
    const float* src; _Float16* dst; int Nd, n0, k0;
    if (id < 256)      { src = wg; dst = wT;            Nd = 512; n0 = (id & 15) * 32;        k0 = (id >> 4) * 32; }
    else if (id < 384) { src = w1; dst = wT + 512*512;  Nd = 256; n0 = ((id-256) & 7) * 32;   k0 = ((id-256) >> 3) * 32; }
    else if (id < 512) { src = w2; dst = wT + 768*512;  Nd = 256; n0 = ((id-384) & 7) * 32;   k0 = ((id-384) >> 3) * 32; }
    else               { src = wz; dst = wzT;           Nd = 512; n0 = ((id-512) & 15) * 32;  k0 = ((id-512) >> 4) * 32; }

    const int t = threadIdx.x;
    const int r = t >> 3, c = (t & 7) * 4;
    *(float4*)&tile[r][c] = *(const float4*)(src + (size_t)(k0 + r) * Nd + n0 + c);
    __syncthreads();
    h4 hv;
    hv.x = (_Float16)tile[c + 0][r];
    hv.y = (_Float16)tile[c + 1][r];
    hv.z = (_Float16)tile[c + 2][r];
    hv.w = (_Float16)tile[c + 3][r];
    *(h4*)(dst + (size_t)(n0 + r) * 512 + k0 + c) = hv;
}

// ---------------------------------------------------------------------------
// k1: MFMA projection GEMM.  BM=64 rows x BN=256 cols, BK=64, 4 waves.
// blockIdx.y = col-block: 0,1 -> x_prime (h2-packed xph), 2 -> x1 (x1p),
// 3 -> x2 (fragment-native x2tn via LDS tile T[ep][key]).
// ---------------------------------------------------------------------------
__global__ __launch_bounds__(256) void k1_mfma(
    const float* __restrict__ x, const _Float16* __restrict__ wT,
    const float* __restrict__ bg, const float* __restrict__ b1,
    const float* __restrict__ b2,
    float* __restrict__ xph, float* __restrict__ x1p, float4* __restrict__ x2tn4)
{
    __shared__ __align__(16) char lds_raw[40960];
    _Float16* Alds = (_Float16*)lds_raw;             // [64][64] f16 = 8 KB
    _Float16* Blds = (_Float16*)(lds_raw + 8192);    // [256][64] f16 = 32 KB

    const int t = threadIdx.x;
    const int m0 = blockIdx.x * 64;
    const int cb = blockIdx.y;
    const int n0 = cb * 256;                         // row base in wT
    const int lane = t & 63, w = t >> 6;
    const int arow = lane & 15, ak = (lane >> 4) * 8;

    f32x4 acc[4][4];
    #pragma unroll
    for (int i = 0; i < 4; ++i)
        #pragma unroll
        for (int j = 0; j < 4; ++j) acc[i][j] = (f32x4){0.f, 0.f, 0.f, 0.f};

    for (int k0 = 0; k0 < 512; k0 += 64) {
        __syncthreads();
        {   // stage A: 64 rows x 64 k fp32 -> f16
            const int r = t >> 2, c0 = (t & 3) * 16;
            const float* src = x + (size_t)(m0 + r) * 512 + k0 + c0;
            #pragma unroll
            for (int hvi = 0; hvi < 2; ++hvi) {
                float4 u0 = *(const float4*)(src + hvi * 8);
                float4 u1 = *(const float4*)(src + hvi * 8 + 4);
                h8 hv;
                hv[0] = (_Float16)u0.x; hv[1] = (_Float16)u0.y;
                hv[2] = (_Float16)u0.z; hv[3] = (_Float16)u0.w;
                hv[4] = (_Float16)u1.x; hv[5] = (_Float16)u1.y;
                hv[6] = (_Float16)u1.z; hv[7] = (_Float16)u1.w;
                *(h8*)(Alds + r * 64 + c0 + hvi * 8) = hv;
            }
        }
        {   // stage B: 256 n-rows x 64 k f16.  8 lanes cover one 128B row.
            #pragma unroll
            for (int i = 0; i < 8; ++i) {
                int idx = t + i * 256;               // 0..2047
                int row = idx >> 3, ch = idx & 7;
                *(float4*)(Blds + row * 64 + ch * 8) =
                    *(const float4*)(wT + (size_t)(n0 + row) * 512 + k0 + ch * 8);
            }
        }
        __syncthreads();

        #pragma unroll
        for (int kk = 0; kk < 2; ++kk) {
            h8 af[4], bf[4];
            #pragma unroll
            for (int rb = 0; rb < 4; ++rb)
                af[rb] = *(const h8*)(Alds + (rb * 16 + arow) * 64 + kk * 32 + ak);
            #pragma unroll
            for (int cf = 0; cf < 4; ++cf)
                bf[cf] = *(const h8*)(Blds + (w * 64 + cf * 16 + arow) * 64 + kk * 32 + ak);
            #pragma unroll
            for (int rb = 0; rb < 4; ++rb)
                #pragma unroll
                for (int cf = 0; cf < 4; ++cf)
                    acc[rb][cf] = __builtin_amdgcn_mfma_f32_16x16x32_f16(
                        af[rb], bf[cf], acc[rb][cf], 0, 0, 0);
        }
    }

    const float* bias = (cb < 2) ? (bg + cb * 256) : (cb == 2 ? b1 : b2);

    if (cb < 3) {
        // pack e-pairs via lane shuffle; even lanes store 4B
        float* dst; int epbase; size_t rstr;
        if (cb < 2) { dst = xph; epbase = cb * 128; rstr = 256; }
        else        { dst = x1p; epbase = 0;        rstr = 128; }
        #pragma unroll
        for (int cf = 0; cf < 4; ++cf) {
            const int c = w * 64 + cf * 16 + arow;
            const float bv = bias[c];
            #pragma unroll
            for (int rb = 0; rb < 4; ++rb) {
                #pragma unroll
                for (int j = 0; j < 4; ++j) {
                    float v = acc[rb][cf][j] + bv;
                    float o = __shfl_xor(v, 1);
                    if ((lane & 1) == 0) {
                        int row = m0 + rb * 16 + (lane >> 4) * 4 + j;
                        dst[(size_t)row * rstr + epbase + (c >> 1)] = packh2(v, o);
                    }
                }
            }
        }
    } else {
        // x2: pack pairs -> LDS tile T[ep][key_local] (stride 68), then emit
        // fragment-native x2tn (coalesced 16B/lane stores).
        __syncthreads();                              // done with Alds/Blds
        float* T = (float*)lds_raw;                   // [128][68] floats = 34816 B
        #pragma unroll
        for (int cf = 0; cf < 4; ++cf) {
            const int c = w * 64 + cf * 16 + arow;
            const float bv = bias[c];
            #pragma unroll
            for (int rb = 0; rb < 4; ++rb) {
                #pragma unroll
                for (int j = 0; j < 4; ++j) {
                    float v = acc[rb][cf][j] + bv;
                    float o = __shfl_xor(v, 1);
                    if ((lane & 1) == 0)
                        T[(c >> 1) * 68 + rb * 16 + (lane >> 4) * 4 + j] = packh2(v, o);
                }
            }
        }
        __syncthreads();
        const int bb = m0 >> 11, j0 = m0 & 2047;      // 4 j-tiles: (j0>>4)+0..3
        #pragma unroll
        for (int g = 0; g < 8; ++g) {
            int slot = t + g * 256;                   // 0..2047
            int jt = slot >> 9;                       // 0..3
            int ks = (slot >> 6) & 7;                 // 0..7
            int l  = slot & 63;
            int eg = l >> 4, jc = l & 15;
            const float* Tp = T + (ks * 16 + eg * 4) * 68 + jt * 16 + jc;
            float4 v;
            v.x = Tp[0]; v.y = Tp[68]; v.z = Tp[136]; v.w = Tp[204];
            x2tn4[(((size_t)bb * 128 + (j0 >> 4) + jt) * 8 + ks) * 64 + l] = v;
        }
    }
}

// ---------------------------------------------------------------------------
// k2: 512 threads (8 waves), 16 rows/block, 2 blocks/CU (74 KB LDS).
// Block mapping: batch = blockIdx.x & 7 (XCD affinity), rowblock = bid >> 3.
// Half order staggered by rowblock parity.  Per key-half h:
//   Phase A(h): wave w computes keys [h*1024+w*128, +128) as 8 tiles x
//     8 k-steps; B fragments = one coalesced float4/lane per (tile,ks)
//     from x2tn -> scU[16][1024] u-packed.
//   Phase B(h): wave w rows {2w,2w+1}: 30th value by binary search with
//     exact-count early exit; compaction -> cand.
// Final: top-30 of 60 + rowmax; unpack; softmax; h2-packed gather.
// ---------------------------------------------------------------------------
__global__ __launch_bounds__(512, 4) void k2_attn(
    const float* __restrict__ x1p, const float4* __restrict__ x2tn4,
    const float* __restrict__ xph, const int* __restrict__ xlen,
    float* __restrict__ yah)
{
    __shared__ unsigned scU[16][1024];            // 64 KB (reused per half)
    __shared__ unsigned cand[16][64];             // 4 KB candidates
    __shared__ unsigned tkp[16][30];
    __shared__ float    wvs[16][30];
    __shared__ int      tki[16][30];
    __shared__ float    vin[16];
    __shared__ unsigned rowmax[16];
    __shared__ int      cntA[16][2];
    __shared__ int      cntF[16];

    const int t  = threadIdx.x;
    const int b  = blockIdx.x & 7;                // batch-per-XCD affinity
    const int i0 = (blockIdx.x >> 3) * 16;
    const int hfirst = (blockIdx.x >> 3) & 1;     // stagger half order
    const int len = xlen[b];
    const int lane = t & 63, wid = t >> 6;        // 8 waves

    ((unsigned*)cand)[t] = 0u;                    // 1024 entries, 2/thread
    ((unsigned*)cand)[t + 512] = 0u;
    if (t < 32) cntA[t >> 1][t & 1] = 0;
    if (t < 16) cntF[t] = 0;

    // A fragments (shared across both halves): row = lane&15, k = (lane>>4)*8
    h8 afr[8];
    {
        const int ar = lane & 15;
        const float* x1row = x1p + ((size_t)b * 2048 + i0 + ar) * 128 + (lane >> 4) * 4;
        #pragma unroll
        for (int ks = 0; ks < 8; ++ks)
            afr[ks] = *(const h8*)(x1row + ks * 16);
    }

    const float4* x2b = x2tn4 + ((size_t)b * 128) * 8 * 64 + lane;
    const int jcol  = lane & 15;
    const int rbase = (lane >> 4) * 4;            // C row base

#define LOADT(H, NT, DST)                                                   \
    {                                                                       \
        const float4* pb_ = x2b + (size_t)(((H) * 64 + wid * 8 + (NT)) * 8) * 64; \
        _Pragma("unroll")                                                   \
        for (int ks = 0; ks < 8; ++ks)                                      \
            DST[ks] = *(const h8*)(pb_ + ks * 64);                          \
    }

#define MFMAT(H, NT, SRC)                                                   \
    {                                                                       \
        const int j_ = (H) * 1024 + wid * 128 + (NT) * 16 + jcol;           \
        const int cs_ = wid * 128 + (NT) * 16 + jcol;                       \
        f32x4 acc = (f32x4){0.f, 0.f, 0.f, 0.f};                            \
        _Pragma("unroll")                                                   \
        for (int ks = 0; ks < 8; ++ks)                                      \
            acc = __builtin_amdgcn_mfma_f32_16x16x32_f16(afr[ks], SRC[ks], acc, 0, 0, 0); \
        const unsigned tag = (unsigned)(2047 - j_);                         \
        const bool valid = (j_ < len);                                      \
        _Pragma("unroll")                                                   \
        for (int jj = 0; jj < 4; ++jj) {                                    \
            unsigned bb = __float_as_uint(acc[jj]);                         \
            bb = bb ^ (0x80000000u | (unsigned)((int)bb >> 31));            \
            scU[rbase + jj][cs_] = valid ? ((bb & 0xFFFFF800u) | tag) : 0u; \
        }                                                                   \
    }

    for (int hh = 0; hh < 2; ++hh) {
        const int h = hfirst ^ hh;                // staggered half order
        {   // phase A(h): 8 tiles, 2-deep prefetch
            h8 va[8], vb[8];
            LOADT(h, 0, va)
            LOADT(h, 1, vb)
            MFMAT(h, 0, va)  LOADT(h, 2, va)
            MFMAT(h, 1, vb)  LOADT(h, 3, vb)
            MFMAT(h, 2, va)  LOADT(h, 4, va)
            MFMAT(h, 3, vb)  LOADT(h, 5, vb)
            MFMAT(h, 4, va)  LOADT(h, 6, va)
            MFMAT(h, 5, vb)  LOADT(h, 7, vb)
            MFMAT(h, 6, va)
            MFMAT(h, 7, vb)
        }
        __syncthreads();

        // phase B(h): wave wid owns rows {2*wid, 2*wid+1}
        #pragma unroll
        for (int rr = 0; rr < 2; ++rr) {
            const int row = wid * 2 + rr;
            unsigned u0[16];
            #pragma unroll
            for (int c = 0; c < 4; ++c)
                *(uint4*)&u0[c * 4] = *(const uint4*)&scU[row][lane * 4 + c * 256];

            unsigned P = 0u;
            for (int bit = 31; bit >= 0; --bit) {
                const unsigned cd = P | (1u << bit);
                int cnt = 0;
                #pragma unroll
                for (int q = 0; q < 16; ++q)
                    cnt += (int)__popcll(__ballot(u0[q] >= cd));
                if (cnt >= 30) {
                    P = cd;
                    if (cnt == 30) break;         // exact: {v>=P} IS the top-30
                }
            }
            #pragma unroll
            for (int q = 0; q < 16; ++q) {
                if (u0[q] >= P && u0[q] != 0u) {
                    int s = atomicAdd(&cntA[row][h], 1);
                    cand[row][h * 30 + s] = u0[q];
                }
            }
        }
        __syncthreads();                          // also guards scU reuse
    }
#undef LOADT
#undef MFMAT

    // ---- final: top-30 of 60 candidates + rowmax; wave wid rows {2w,2w+1} ----
    #pragma unroll
    for (int rr = 0; rr < 2; ++rr) {
        const int row = wid * 2 + rr;
        unsigned v = (lane < 60) ? cand[row][lane] : 0u;
        unsigned lm = v;
        #pragma unroll
        for (int off = 32; off > 0; off >>= 1) {
            unsigned o = (unsigned)__shfl_xor((int)lm, off);
            lm = lm > o ? lm : o;
        }
        if (lane == 0) rowmax[row] = lm;

        unsigned P = 0u;
        for (int bit = 31; bit >= 0; --bit) {
            const unsigned cd = P | (1u << bit);
            int cnt = (int)__popcll(__ballot(v >= cd));
            if (cnt >= 30) {
                P = cd;
                if (cnt == 30) break;             // exact early exit
            }
        }
        if (v >= P && v != 0u) {
            int s = atomicAdd(&cntF[row], 1);
            tkp[row][s] = v;
        }
    }
    __syncthreads();

    // ---- unpack + per-row softmax weights (base = rowmax) ----
    {
        const int r = t >> 5, k = t & 31;         // 32 threads per row
        if (k < 30) {
            unsigned u = tkp[r][k];
            unsigned m0 = rowmax[r] & 0xFFFFF800u;
            unsigned ub = u & 0xFFFFF800u;
            unsigned bb0 = (m0 & 0x80000000u) ? (m0 ^ 0x80000000u) : ~m0;
            unsigned bbk = (ub & 0x80000000u) ? (ub ^ 0x80000000u) : ~ub;
            float s0 = __uint_as_float(bb0);
            float sk = __uint_as_float(bbk);
            wvs[r][k] = __expf(sk - s0);
            tki[r][k] = 2047 - (int)(u & 0x7FFu);
        }
    }
    __syncthreads();
    if (t < 16) {
        float s = 0.f;
        #pragma unroll
        for (int k = 0; k < 30; ++k) s += wvs[t][k];
        vin[t] = 1.f / s;
    }
    __syncthreads();

    // ---- phase C: gather of h2-packed x_prime; 256 threads per 8 rows ----
    const int g  = t >> 8;                        // 0..1 -> rows g*8..g*8+8
    const int hp = t & 255;                       // h2-pair index
    for (int r = g * 8; r < g * 8 + 8; ++r) {
        float y0 = 0.f, y1 = 0.f;
        #pragma unroll
        for (int k = 0; k < 30; ++k) {
            int j = tki[r][k];
            float wv = wvs[r][k];
            h2 u = as_h2(xph[((size_t)b * 2048 + j) * 256 + hp]);
            y0 = fmaf(wv, (float)u.x, y0);
            y1 = fmaf(wv, (float)u.y, y1);
        }
        const float inv = vin[r];
        yah[((size_t)b * 2048 + i0 + r) * 256 + hp] = packh2(y0 * inv, y1 * inv);
    }
}

// ---------------------------------------------------------------------------
// k3: out = x + yah @ wzT^T + bz.  MFMA, BM=64, BN=256 (2 col-blocks), BK=64.
// ---------------------------------------------------------------------------
__global__ __launch_bounds__(256) void k3_mfma(
    const float* __restrict__ yah, const _Float16* __restrict__ wzT,
    const float* __restrict__ bz, const float* __restrict__ x,
    float* __restrict__ out)
{
    __shared__ __align__(16) char lds_raw[40960];
    _Float16* Alds = (_Float16*)lds_raw;             // [64][64]
    _Float16* Blds = (_Float16*)(lds_raw + 8192);    // [256][64]

    const int t = threadIdx.x;
    const int m0 = blockIdx.x * 64;
    const int n0 = blockIdx.y * 256;
    const int lane = t & 63, w = t >> 6;
    const int arow = lane & 15, ak = (lane >> 4) * 8;

    f32x4 acc[4][4];
    #pragma unroll
    for (int i = 0; i < 4; ++i)
        #pragma unroll
        for (int j = 0; j < 4; ++j) acc[i][j] = (f32x4){0.f, 0.f, 0.f, 0.f};

    for (int k0 = 0; k0 < 512; k0 += 64) {
        __syncthreads();
        {   // stage A: h2-packed rows, pure copy. 64 rows x 32 floats
            const int r = t >> 2, c0 = (t & 3) * 8;   // float chunk
            const float4* src = (const float4*)(yah + (size_t)(m0 + r) * 256 + k0 / 2 + c0);
            float4* dst = (float4*)(Alds + r * 64 + c0 * 2);
            dst[0] = src[0]; dst[1] = src[1];
        }
        {   // stage B: 256 n-rows x 64 k f16.  8 lanes cover one 128B row.
            #pragma unroll
            for (int i = 0; i < 8; ++i) {
                int idx = t + i * 256;               // 0..2047
                int row = idx >> 3, ch = idx & 7;
                *(float4*)(Blds + row * 64 + ch * 8) =
                    *(const float4*)(wzT + (size_t)(n0 + row) * 512 + k0 + ch * 8);
            }
        }
        __syncthreads();

        #pragma unroll
        for (int kk = 0; kk < 2; ++kk) {
            h8 af[4], bf[4];
            #pragma unroll
            for (int rb = 0; rb < 4; ++rb)
                af[rb] = *(const h8*)(Alds + (rb * 16 + arow) * 64 + kk * 32 + ak);
            #pragma unroll
            for (int cf = 0; cf < 4; ++cf)
                bf[cf] = *(const h8*)(Blds + (w * 64 + cf * 16 + arow) * 64 + kk * 32 + ak);
            #pragma unroll
            for (int rb = 0; rb < 4; ++rb)
                #pragma unroll
                for (int cf = 0; cf < 4; ++cf)
                    acc[rb][cf] = __builtin_amdgcn_mfma_f32_16x16x32_f16(
                        af[rb], bf[cf], acc[rb][cf], 0, 0, 0);
        }
    }

    #pragma unroll
    for (int cf = 0; cf < 4; ++cf) {
        const int c = n0 + w * 64 + cf * 16 + arow;
        const float bv = bz[c];
        #pragma unroll
        for (int rb = 0; rb < 4; ++rb) {
            #pragma unroll
            for (int j = 0; j < 4; ++j) {
                int row = m0 + rb * 16 + (lane >> 4) * 4 + j;
                out[(size_t)row * 512 + c] =
                    acc[rb][cf][j] + bv + x[(size_t)row * 512 + c];
            }
        }
    }
}

extern "C" void kernel_launch(void* const* d_in, const int* in_sizes, int n_in,
                              void* d_out, int out_size, void* d_ws, size_t ws_size,
                              hipStream_t stream)
{
    (void)in_sizes; (void)n_in; (void)out_size; (void)ws_size;

    const float* x   = (const float*)d_in[0];
    const float* wg  = (const float*)d_in[1];
    const float* bg  = (const float*)d_in[2];
    const float* w1  = (const float*)d_in[3];
    const float* b1  = (const float*)d_in[4];
    const float* w2  = (const float*)d_in[5];
    const float* b2  = (const float*)d_in[6];
    const float* wzw = (const float*)d_in[7];
    const float* wzb = (const float*)d_in[8];
    const int* xlen  = (const int*)d_in[9];
    float* outp      = (float*)d_out;

    char* ws = (char*)d_ws;
    _Float16* wT   = (_Float16*)(ws);                       // 1 MiB [1024][512] f16
    _Float16* wzT  = (_Float16*)(ws + 1u * 1024 * 1024);    // 0.5 MiB [512][512] f16
    float* x1pw    = (float*)(ws +  2u * 1024 * 1024);      // 8 MiB [16384][128] h2
    float4* x2tnw  = (float4*)(ws + 10u * 1024 * 1024);     // 8 MiB [8][128][8][64] float4
    float* xphw    = (float*)(ws + 18u * 1024 * 1024);      // 16 MiB [16384][256] h2
    float* yahw    = (float*)(ws + 34u * 1024 * 1024);      // 16 MiB [16384][256] h2

    hipLaunchKernelGGL(k0_pack, dim3(768), dim3(256), 0, stream,
                       wg, w1, w2, wzw, wT, wzT);
    hipLaunchKernelGGL(k1_mfma, dim3(256, 4), dim3(256), 0, stream,
                       x, wT, bg, b1, b2, xphw, x1pw, x2tnw);
    hipLaunchKernelGGL(k2_attn, dim3(1024), dim3(512), 0, stream,
                       x1pw, x2tnw, xphw, xlen, yahw);
    hipLaunchKernelGGL(k3_mfma, dim3(256, 2), dim3(256), 0, stream,
                       yahw, wzT, wzb, x, outp);
}